// Round 5
// baseline (373.146 us; speedup 1.0000x reference)
//
#include <hip/hip_runtime.h>
#include <hip/hip_cooperative_groups.h>
#include <math.h>

namespace cg = cooperative_groups;

#define TOKENS 16384
#define EXPERTS 64
#define DIM 2048
#define BETA 0.5f
#define EPSILON 0.05f
#define EPSN 1e-12f
#define COLMASS 256.0f           // B/E = 16384/64

// ws layout (float offsets)
#define OFF_ENORM   0            // 64*2048 fp32 e_norm rows
#define OFF_BBF     131072       // 131072 ushorts: bf16 B in MFMA-fragment order
#define OFF_M       262144       // 64*64
#define OFF_LOGK    266240       // 16384*64
#define OFF_COLS    1314816      // 5*64 column-sum accumulators
// total < 1.32M floats = 5.3 MB

// out layout (float offsets): probs 0, sim 1048576, gram 2097152, gram_off 2101248

typedef __attribute__((ext_vector_type(8))) short short8v;   // 8 bf16 (4 VGPR)
typedef __attribute__((ext_vector_type(4))) float f32x4;

static __device__ __forceinline__ unsigned short f2bf(float f) {
  unsigned int u = __float_as_uint(f);
  u += 0x7FFFu + ((u >> 16) & 1u);   // round-to-nearest-even
  return (unsigned short)(u >> 16);
}

// ---------------- K1: normalize expert rows -> e_norm fp32 + bf16 B-fragment table ----------------
// Bbf layout: flat = (k>>5)*2048 + expert*32 + (k&31)
__global__ __launch_bounds__(256) void k1_norm_experts(const float* __restrict__ ex,
                                                       float* __restrict__ ws) {
  int j = blockIdx.x, t = threadIdx.x;
  // zero the Sinkhorn column-sum accumulators (ws is re-poisoned before every launch)
  if (j < 5 && t < 64) ws[OFF_COLS + j * 64 + t] = 0.0f;
  const float4* row4 = (const float4*)(ex + (size_t)j * DIM);
  float4 v0 = row4[t];
  float4 v1 = row4[t + 256];
  float ss = v0.x*v0.x + v0.y*v0.y + v0.z*v0.z + v0.w*v0.w
           + v1.x*v1.x + v1.y*v1.y + v1.z*v1.z + v1.w*v1.w;
  #pragma unroll
  for (int m = 1; m < 64; m <<= 1) ss += __shfl_xor(ss, m);
  __shared__ float red[4];
  int wv = t >> 6, ln = t & 63;
  if (ln == 0) red[wv] = ss;
  __syncthreads();
  float tot = red[0] + red[1] + red[2] + red[3];
  float sc = 1.0f / fmaxf(sqrtf(tot), EPSN);
  float4 w0 = make_float4(v0.x*sc, v0.y*sc, v0.z*sc, v0.w*sc);
  float4 w1 = make_float4(v1.x*sc, v1.y*sc, v1.z*sc, v1.w*sc);
  float4* en4 = (float4*)(ws + OFF_ENORM + (size_t)j * DIM);
  en4[t] = w0;
  en4[t + 256] = w1;
  unsigned short* Bb = (unsigned short*)(ws + OFF_BBF);
  int k0 = t * 4;
  int i0 = ((k0 >> 5) << 11) + (j << 5) + (k0 & 31);
  ushort4 u0; u0.x = f2bf(w0.x); u0.y = f2bf(w0.y); u0.z = f2bf(w0.z); u0.w = f2bf(w0.w);
  *(ushort4*)(Bb + i0) = u0;
  int k1v = (t + 256) * 4;
  int i1 = ((k1v >> 5) << 11) + (j << 5) + (k1v & 31);
  ushort4 u1; u1.x = f2bf(w1.x); u1.y = f2bf(w1.y); u1.z = f2bf(w1.z); u1.w = f2bf(w1.w);
  *(ushort4*)(Bb + i1) = u1;
}

// ---------------- K2: gram, gram_off, M = I - beta*gram_off ----------------
__global__ __launch_bounds__(256) void k2_gram(const float* __restrict__ wsr,
                                               float* __restrict__ ws,
                                               float* __restrict__ out) {
  __shared__ __align__(16) float ej[DIM];
  __shared__ float part[4][64];
  int j = blockIdx.x, t = threadIdx.x;
  const float4* en4 = (const float4*)(wsr + OFF_ENORM + (size_t)j * DIM);
  ((float4*)ej)[t] = en4[t];
  ((float4*)ej)[t + 256] = en4[t + 256];
  __syncthreads();
  int kk = t & 63, q = t >> 6;
  const float4* er = (const float4*)(wsr + OFF_ENORM + (size_t)kk * DIM) + q * 128;
  const float4* ejq = (const float4*)ej + q * 128;
  float p = 0.f;
  #pragma unroll 4
  for (int i = 0; i < 128; ++i) {
    float4 a = ejq[i], b = er[i];
    p += a.x*b.x + a.y*b.y + a.z*b.z + a.w*b.w;
  }
  part[q][kk] = p;
  __syncthreads();
  if (t < 64) {
    float g = part[0][t] + part[1][t] + part[2][t] + part[3][t];
    out[2097152 + j*64 + t] = g;
    float go = fmaxf(g - (t == j ? 1.0f : 0.0f), 0.0f);
    out[2101248 + j*64 + t] = go;
    ws[OFF_M + j*64 + t] = (t == j ? 1.0f : 0.0f) - BETA * go;
  }
}

// ---------------- K3: fused x-norm + sim (bf16 MFMA) + sim@M/eps -> logK ----------------
__global__ __launch_bounds__(256) void k3_main(const float* __restrict__ x,
                                               const float* __restrict__ wsr,
                                               float* __restrict__ ws,
                                               float* __restrict__ out) {
  __shared__ __align__(16) unsigned short A_lds[32 * 64];
  __shared__ __align__(16) float Ml[64 * 64];
  __shared__ __align__(16) float simL[32 * 68];
  __shared__ float sqL[32][8];
  __shared__ float scaleL[32];

  const int t = threadIdx.x;
  const int r0 = blockIdx.x * 32;

  const int srow = t >> 3;
  const int sk8  = (t & 7) << 3;
  const float* xrow = x + (size_t)(r0 + srow) * DIM + sk8;
  char* Ab = (char*)A_lds;
  const int wbyte = (srow * 128 + ((t & 7) << 4)) ^ ((srow & 7) << 4);

  const int l = t & 63, w = t >> 6;
  const int rw = w & 1;
  const int tcA = (w >> 1) << 1;
  const int arow = rw * 16 + (l & 15);
  const int abyte0 = (arow * 128 + ((l >> 4) << 4)) ^ ((arow & 7) << 4);
  const int abyte1 = (arow * 128 + ((4 + (l >> 4)) << 4)) ^ ((arow & 7) << 4);
  const unsigned short* Bws = (const unsigned short*)(wsr + OFF_BBF);
  const int boffA = ((tcA * 16 + (l & 15)) << 5) + ((l >> 4) << 3);
  const int boffB = boffA + (16 << 5);

  f32x4 acc0 = {0.f, 0.f, 0.f, 0.f};
  f32x4 acc1 = {0.f, 0.f, 0.f, 0.f};
  float nsq = 0.f;

  float4 a0 = *(const float4*)xrow;
  float4 a1 = *(const float4*)(xrow + 4);

  for (int c = 0; c < 32; ++c) {
    float4 c0 = a0, c1 = a1;
    if (c < 31) {
      const float* nx = xrow + (c + 1) * 64;
      a0 = *(const float4*)nx;
      a1 = *(const float4*)(nx + 4);
    }
    const unsigned short* bp = Bws + (size_t)(c * 2) * 2048;
    short8v b00 = *(const short8v*)(bp + boffA);
    short8v b01 = *(const short8v*)(bp + boffB);
    short8v b10 = *(const short8v*)(bp + 2048 + boffA);
    short8v b11 = *(const short8v*)(bp + 2048 + boffB);

    nsq += c0.x*c0.x + c0.y*c0.y + c0.z*c0.z + c0.w*c0.w
         + c1.x*c1.x + c1.y*c1.y + c1.z*c1.z + c1.w*c1.w;
    short8v av;
    av[0] = (short)f2bf(c0.x); av[1] = (short)f2bf(c0.y);
    av[2] = (short)f2bf(c0.z); av[3] = (short)f2bf(c0.w);
    av[4] = (short)f2bf(c1.x); av[5] = (short)f2bf(c1.y);
    av[6] = (short)f2bf(c1.z); av[7] = (short)f2bf(c1.w);
    *(short8v*)(Ab + wbyte) = av;
    __syncthreads();
    short8v af0 = *(const short8v*)(Ab + abyte0);
    short8v af1 = *(const short8v*)(Ab + abyte1);
    acc0 = __builtin_amdgcn_mfma_f32_16x16x32_bf16(af0, b00, acc0, 0, 0, 0);
    acc1 = __builtin_amdgcn_mfma_f32_16x16x32_bf16(af0, b01, acc1, 0, 0, 0);
    acc0 = __builtin_amdgcn_mfma_f32_16x16x32_bf16(af1, b10, acc0, 0, 0, 0);
    acc1 = __builtin_amdgcn_mfma_f32_16x16x32_bf16(af1, b11, acc1, 0, 0, 0);
    __syncthreads();
  }

  sqL[srow][t & 7] = nsq;
  {
    const float4* Mw = (const float4*)(wsr + OFF_M);
    float4* Ml4 = (float4*)Ml;
    #pragma unroll
    for (int s = 0; s < 4; ++s) Ml4[s * 256 + t] = Mw[s * 256 + t];
  }
  __syncthreads();
  if (t < 32) {
    float tot = 0.f;
    #pragma unroll
    for (int i = 0; i < 8; ++i) tot += sqL[t][i];
    scaleL[t] = 1.0f / fmaxf(sqrtf(tot), EPSN);
  }
  __syncthreads();

  float* simOut = out + 1048576;
  const int colA = tcA * 16 + (l & 15);
  #pragma unroll
  for (int j = 0; j < 4; ++j) {
    int rr = rw * 16 + ((l >> 4) << 2) + j;
    float sc = scaleL[rr];
    float s0 = acc0[j] * sc, s1 = acc1[j] * sc;
    simL[rr * 68 + colA]      = s0;
    simL[rr * 68 + colA + 16] = s1;
    simOut[(size_t)(r0 + rr) * 64 + colA]      = s0;
    simOut[(size_t)(r0 + rr) * 64 + colA + 16] = s1;
  }
  __syncthreads();

  const int tr = t >> 4, tc = t & 15;
  float lk0[4] = {0.f,0.f,0.f,0.f}, lk1[4] = {0.f,0.f,0.f,0.f};
  #pragma unroll 8
  for (int j = 0; j < 64; ++j) {
    float4 mj = *(const float4*)&Ml[j * 64 + (tc << 2)];
    float s0 = simL[(tr * 2) * 68 + j];
    float s1 = simL[(tr * 2 + 1) * 68 + j];
    lk0[0] += s0*mj.x; lk0[1] += s0*mj.y; lk0[2] += s0*mj.z; lk0[3] += s0*mj.w;
    lk1[0] += s1*mj.x; lk1[1] += s1*mj.y; lk1[2] += s1*mj.z; lk1[3] += s1*mj.w;
  }
  float* logK = ws + OFF_LOGK;
  const float ie = 1.0f / EPSILON;
  float4 o0 = make_float4(lk0[0]*ie, lk0[1]*ie, lk0[2]*ie, lk0[3]*ie);
  float4 o1 = make_float4(lk1[0]*ie, lk1[1]*ie, lk1[2]*ie, lk1[3]*ie);
  *(float4*)(logK + (size_t)(r0 + tr*2    ) * 64 + (tc << 2)) = o0;
  *(float4*)(logK + (size_t)(r0 + tr*2 + 1) * 64 + (tc << 2)) = o1;
}

// ---------------- KS: cooperative multiplicative Sinkhorn + final probs ----------------
// 256 blocks x 256 threads. Block b owns rows b*64..b*64+63; thread: row t>>2, cols (t&3)*16..+15.
// u = 1/(K c); c = (B/E)/(K^T u); after 5 iters P = u*K*c. Matches log-domain reference exactly.
__global__ __launch_bounds__(256) void kS_sinkhorn(const float* __restrict__ logK,
                                                   float* __restrict__ colsums,
                                                   float* __restrict__ out) {
  cg::grid_group grid = cg::this_grid();
  __shared__ float cps[4][64];
  __shared__ float cL[64];
  const int t = threadIdx.x, b = blockIdx.x;
  const int q = t & 3;
  const int row = b * 64 + (t >> 2);
  const float4* lr = (const float4*)(logK + (size_t)row * 64 + q * 16);
  float4 A0 = lr[0], A1 = lr[1], A2 = lr[2], A3 = lr[3];
  float k[16] = {A0.x,A0.y,A0.z,A0.w, A1.x,A1.y,A1.z,A1.w,
                 A2.x,A2.y,A2.z,A2.w, A3.x,A3.y,A3.z,A3.w};
  #pragma unroll
  for (int i = 0; i < 16; ++i) k[i] = __expf(k[i]);
  float c[16];
  #pragma unroll
  for (int i = 0; i < 16; ++i) c[i] = 1.0f;
  float u = 0.f;

  for (int it = 0; it < 5; ++it) {
    // row sum (4 lanes per row)
    float s = 0.f;
    #pragma unroll
    for (int i = 0; i < 16; ++i) s += k[i] * c[i];
    s += __shfl_xor(s, 1);
    s += __shfl_xor(s, 2);
    u = 1.0f / s;
    // column partials over this wave's 16 rows
    float pc[16];
    #pragma unroll
    for (int i = 0; i < 16; ++i) pc[i] = k[i] * u;
    #pragma unroll
    for (int i = 0; i < 16; ++i) {
      pc[i] += __shfl_xor(pc[i], 4);
      pc[i] += __shfl_xor(pc[i], 8);
      pc[i] += __shfl_xor(pc[i], 16);
      pc[i] += __shfl_xor(pc[i], 32);
    }
    const int wv = t >> 6, l = t & 63;
    if (l < 4) {
      #pragma unroll
      for (int i = 0; i < 16; ++i) cps[wv][l * 16 + i] = pc[i];
    }
    __syncthreads();
    if (t < 64) {
      float tot = cps[0][t] + cps[1][t] + cps[2][t] + cps[3][t];
      atomicAdd(&colsums[it * 64 + t], tot);
    }
    grid.sync();
    if (t < 64) {
      volatile const float* cv = colsums + it * 64;   // bypass L1; other XCDs' atomics
      cL[t] = COLMASS / cv[t];
    }
    __syncthreads();
    #pragma unroll
    for (int i = 0; i < 16; ++i) c[i] = cL[q * 16 + i];
  }

  // P = u * K * c
  float p[16];
  #pragma unroll
  for (int i = 0; i < 16; ++i) p[i] = u * k[i] * c[i];
  float4* op = (float4*)(out + (size_t)row * 64 + q * 16);
  op[0] = make_float4(p[0], p[1], p[2], p[3]);
  op[1] = make_float4(p[4], p[5], p[6], p[7]);
  op[2] = make_float4(p[8], p[9], p[10], p[11]);
  op[3] = make_float4(p[12], p[13], p[14], p[15]);
}

extern "C" void kernel_launch(void* const* d_in, const int* in_sizes, int n_in,
                              void* d_out, int out_size, void* d_ws, size_t ws_size,
                              hipStream_t stream) {
  const float* x  = (const float*)d_in[0];
  const float* ex = (const float*)d_in[1];
  float* out = (float*)d_out;
  float* ws  = (float*)d_ws;

  k1_norm_experts<<<64, 256, 0, stream>>>(ex, ws);
  k2_gram<<<64, 256, 0, stream>>>(ws, ws, out);
  k3_main<<<512, 256, 0, stream>>>(x, ws, ws, out);

  const float* logK = ws + OFF_LOGK;
  float* cols = ws + OFF_COLS;
  void* args[] = { (void*)&logK, (void*)&cols, (void*)&out };
  hipLaunchCooperativeKernel((const void*)kS_sinkhorn, dim3(256), dim3(256),
                             args, 0, stream);
}

// Round 6
// 266.799 us; speedup vs baseline: 1.3986x; 1.3986x over previous
//
#include <hip/hip_runtime.h>
#include <math.h>

#define TOKENS 16384
#define EXPERTS 64
#define DIM 2048
#define BETA 0.5f
#define EPSILON 0.05f
#define EPSN 1e-12f
#define COLMASS 256.0f           // B/E = 16384/64

// ws layout (float offsets)
#define OFF_ENORM   0            // 64*2048 fp32 e_norm rows
#define OFF_BBF     131072       // 131072 ushorts: bf16 B in MFMA-fragment order
#define OFF_M       262144       // 64*64
#define OFF_EXPK    266240       // 16384*64  expK = exp(sim@M/eps)
#define OFF_COLS    1314816      // 5*64 column-sum accumulators
// total < 1.32M floats = 5.3 MB

// out layout (float offsets): probs 0, sim 1048576, gram 2097152, gram_off 2101248

typedef __attribute__((ext_vector_type(8))) short short8v;   // 8 bf16 (4 VGPR)
typedef __attribute__((ext_vector_type(4))) float f32x4;

static __device__ __forceinline__ unsigned short f2bf(float f) {
  unsigned int u = __float_as_uint(f);
  u += 0x7FFFu + ((u >> 16) & 1u);   // round-to-nearest-even
  return (unsigned short)(u >> 16);
}

// ---------------- K1: normalize expert rows -> e_norm fp32 + bf16 B-fragment table ----------------
// Bbf layout: flat = (k>>5)*2048 + expert*32 + (k&31)
__global__ __launch_bounds__(256) void k1_norm_experts(const float* __restrict__ ex,
                                                       float* __restrict__ ws) {
  int j = blockIdx.x, t = threadIdx.x;
  // zero the Sinkhorn column-sum accumulators (ws is re-poisoned before every launch)
  if (j < 5 && t < 64) ws[OFF_COLS + j * 64 + t] = 0.0f;
  const float4* row4 = (const float4*)(ex + (size_t)j * DIM);
  float4 v0 = row4[t];
  float4 v1 = row4[t + 256];
  float ss = v0.x*v0.x + v0.y*v0.y + v0.z*v0.z + v0.w*v0.w
           + v1.x*v1.x + v1.y*v1.y + v1.z*v1.z + v1.w*v1.w;
  #pragma unroll
  for (int m = 1; m < 64; m <<= 1) ss += __shfl_xor(ss, m);
  __shared__ float red[4];
  int wv = t >> 6, ln = t & 63;
  if (ln == 0) red[wv] = ss;
  __syncthreads();
  float tot = red[0] + red[1] + red[2] + red[3];
  float sc = 1.0f / fmaxf(sqrtf(tot), EPSN);
  float4 w0 = make_float4(v0.x*sc, v0.y*sc, v0.z*sc, v0.w*sc);
  float4 w1 = make_float4(v1.x*sc, v1.y*sc, v1.z*sc, v1.w*sc);
  float4* en4 = (float4*)(ws + OFF_ENORM + (size_t)j * DIM);
  en4[t] = w0;
  en4[t + 256] = w1;
  unsigned short* Bb = (unsigned short*)(ws + OFF_BBF);
  int k0 = t * 4;
  int i0 = ((k0 >> 5) << 11) + (j << 5) + (k0 & 31);
  ushort4 u0; u0.x = f2bf(w0.x); u0.y = f2bf(w0.y); u0.z = f2bf(w0.z); u0.w = f2bf(w0.w);
  *(ushort4*)(Bb + i0) = u0;
  int k1v = (t + 256) * 4;
  int i1 = ((k1v >> 5) << 11) + (j << 5) + (k1v & 31);
  ushort4 u1; u1.x = f2bf(w1.x); u1.y = f2bf(w1.y); u1.z = f2bf(w1.z); u1.w = f2bf(w1.w);
  *(ushort4*)(Bb + i1) = u1;
}

// ---------------- K2: gram, gram_off, M = I - beta*gram_off ----------------
__global__ __launch_bounds__(256) void k2_gram(const float* __restrict__ wsr,
                                               float* __restrict__ ws,
                                               float* __restrict__ out) {
  __shared__ __align__(16) float ej[DIM];
  __shared__ float part[4][64];
  int j = blockIdx.x, t = threadIdx.x;
  const float4* en4 = (const float4*)(wsr + OFF_ENORM + (size_t)j * DIM);
  ((float4*)ej)[t] = en4[t];
  ((float4*)ej)[t + 256] = en4[t + 256];
  __syncthreads();
  int kk = t & 63, q = t >> 6;
  const float4* er = (const float4*)(wsr + OFF_ENORM + (size_t)kk * DIM) + q * 128;
  const float4* ejq = (const float4*)ej + q * 128;
  float p = 0.f;
  #pragma unroll 4
  for (int i = 0; i < 128; ++i) {
    float4 a = ejq[i], b = er[i];
    p += a.x*b.x + a.y*b.y + a.z*b.z + a.w*b.w;
  }
  part[q][kk] = p;
  __syncthreads();
  if (t < 64) {
    float g = part[0][t] + part[1][t] + part[2][t] + part[3][t];
    out[2097152 + j*64 + t] = g;
    float go = fmaxf(g - (t == j ? 1.0f : 0.0f), 0.0f);
    out[2101248 + j*64 + t] = go;
    ws[OFF_M + j*64 + t] = (t == j ? 1.0f : 0.0f) - BETA * go;
  }
}

// ---------------- K3: fused x-norm + sim (bf16 MFMA) + expK = exp(sim@M/eps) ----------------
__global__ __launch_bounds__(256) void k3_main(const float* __restrict__ x,
                                               const float* __restrict__ wsr,
                                               float* __restrict__ ws,
                                               float* __restrict__ out) {
  __shared__ __align__(16) unsigned short A_lds[32 * 64];
  __shared__ __align__(16) float Ml[64 * 64];
  __shared__ __align__(16) float simL[32 * 68];
  __shared__ float sqL[32][8];
  __shared__ float scaleL[32];

  const int t = threadIdx.x;
  const int r0 = blockIdx.x * 32;

  const int srow = t >> 3;
  const int sk8  = (t & 7) << 3;
  const float* xrow = x + (size_t)(r0 + srow) * DIM + sk8;
  char* Ab = (char*)A_lds;
  const int wbyte = (srow * 128 + ((t & 7) << 4)) ^ ((srow & 7) << 4);

  const int l = t & 63, w = t >> 6;
  const int rw = w & 1;
  const int tcA = (w >> 1) << 1;
  const int arow = rw * 16 + (l & 15);
  const int abyte0 = (arow * 128 + ((l >> 4) << 4)) ^ ((arow & 7) << 4);
  const int abyte1 = (arow * 128 + ((4 + (l >> 4)) << 4)) ^ ((arow & 7) << 4);
  const unsigned short* Bws = (const unsigned short*)(wsr + OFF_BBF);
  const int boffA = ((tcA * 16 + (l & 15)) << 5) + ((l >> 4) << 3);
  const int boffB = boffA + (16 << 5);

  f32x4 acc0 = {0.f, 0.f, 0.f, 0.f};
  f32x4 acc1 = {0.f, 0.f, 0.f, 0.f};
  float nsq = 0.f;

  float4 a0 = *(const float4*)xrow;
  float4 a1 = *(const float4*)(xrow + 4);

  for (int c = 0; c < 32; ++c) {
    float4 c0 = a0, c1 = a1;
    if (c < 31) {
      const float* nx = xrow + (c + 1) * 64;
      a0 = *(const float4*)nx;
      a1 = *(const float4*)(nx + 4);
    }
    const unsigned short* bp = Bws + (size_t)(c * 2) * 2048;
    short8v b00 = *(const short8v*)(bp + boffA);
    short8v b01 = *(const short8v*)(bp + boffB);
    short8v b10 = *(const short8v*)(bp + 2048 + boffA);
    short8v b11 = *(const short8v*)(bp + 2048 + boffB);

    nsq += c0.x*c0.x + c0.y*c0.y + c0.z*c0.z + c0.w*c0.w
         + c1.x*c1.x + c1.y*c1.y + c1.z*c1.z + c1.w*c1.w;
    short8v av;
    av[0] = (short)f2bf(c0.x); av[1] = (short)f2bf(c0.y);
    av[2] = (short)f2bf(c0.z); av[3] = (short)f2bf(c0.w);
    av[4] = (short)f2bf(c1.x); av[5] = (short)f2bf(c1.y);
    av[6] = (short)f2bf(c1.z); av[7] = (short)f2bf(c1.w);
    *(short8v*)(Ab + wbyte) = av;
    __syncthreads();
    short8v af0 = *(const short8v*)(Ab + abyte0);
    short8v af1 = *(const short8v*)(Ab + abyte1);
    acc0 = __builtin_amdgcn_mfma_f32_16x16x32_bf16(af0, b00, acc0, 0, 0, 0);
    acc1 = __builtin_amdgcn_mfma_f32_16x16x32_bf16(af0, b01, acc1, 0, 0, 0);
    acc0 = __builtin_amdgcn_mfma_f32_16x16x32_bf16(af1, b10, acc0, 0, 0, 0);
    acc1 = __builtin_amdgcn_mfma_f32_16x16x32_bf16(af1, b11, acc1, 0, 0, 0);
    __syncthreads();
  }

  sqL[srow][t & 7] = nsq;
  {
    const float4* Mw = (const float4*)(wsr + OFF_M);
    float4* Ml4 = (float4*)Ml;
    #pragma unroll
    for (int s = 0; s < 4; ++s) Ml4[s * 256 + t] = Mw[s * 256 + t];
  }
  __syncthreads();
  if (t < 32) {
    float tot = 0.f;
    #pragma unroll
    for (int i = 0; i < 8; ++i) tot += sqL[t][i];
    scaleL[t] = 1.0f / fmaxf(sqrtf(tot), EPSN);
  }
  __syncthreads();

  float* simOut = out + 1048576;
  const int colA = tcA * 16 + (l & 15);
  #pragma unroll
  for (int j = 0; j < 4; ++j) {
    int rr = rw * 16 + ((l >> 4) << 2) + j;
    float sc = scaleL[rr];
    float s0 = acc0[j] * sc, s1 = acc1[j] * sc;
    simL[rr * 68 + colA]      = s0;
    simL[rr * 68 + colA + 16] = s1;
    simOut[(size_t)(r0 + rr) * 64 + colA]      = s0;
    simOut[(size_t)(r0 + rr) * 64 + colA + 16] = s1;
  }
  __syncthreads();

  const int tr = t >> 4, tc = t & 15;
  float lk0[4] = {0.f,0.f,0.f,0.f}, lk1[4] = {0.f,0.f,0.f,0.f};
  #pragma unroll 8
  for (int j = 0; j < 64; ++j) {
    float4 mj = *(const float4*)&Ml[j * 64 + (tc << 2)];
    float s0 = simL[(tr * 2) * 68 + j];
    float s1 = simL[(tr * 2 + 1) * 68 + j];
    lk0[0] += s0*mj.x; lk0[1] += s0*mj.y; lk0[2] += s0*mj.z; lk0[3] += s0*mj.w;
    lk1[0] += s1*mj.x; lk1[1] += s1*mj.y; lk1[2] += s1*mj.z; lk1[3] += s1*mj.w;
  }
  float* expK = ws + OFF_EXPK;
  const float ie = 1.0f / EPSILON;
  float4 o0 = make_float4(__expf(lk0[0]*ie), __expf(lk0[1]*ie),
                          __expf(lk0[2]*ie), __expf(lk0[3]*ie));
  float4 o1 = make_float4(__expf(lk1[0]*ie), __expf(lk1[1]*ie),
                          __expf(lk1[2]*ie), __expf(lk1[3]*ie));
  *(float4*)(expK + (size_t)(r0 + tr*2    ) * 64 + (tc << 2)) = o0;
  *(float4*)(expK + (size_t)(r0 + tr*2 + 1) * 64 + (tc << 2)) = o1;
}

// ---------------- K4<IT>: one mult-Sinkhorn iteration; kernel boundary = barrier ----------------
// Block b owns rows b*64..+63. Thread: row t>>2, cols (t&3)*16..+15.
// u = 1/(K c_IT); colsums[IT] += K^T u  (c_{IT} = COLMASS/colsums[IT-1], c_0 = 1)
template<int IT>
__global__ __launch_bounds__(256) void k4_iter(const float* __restrict__ expK,
                                               float* __restrict__ colsums) {
  __shared__ float cps[4][64];
  __shared__ float cL[64];
  const int t = threadIdx.x, b = blockIdx.x;
  if (t < 64) cL[t] = (IT == 0) ? 1.0f : (COLMASS / colsums[(IT - 1) * 64 + t]);
  __syncthreads();
  const int q = t & 3;
  const int row = b * 64 + (t >> 2);
  const float4* lr = (const float4*)(expK + (size_t)row * 64 + q * 16);
  float4 A0 = lr[0], A1 = lr[1], A2 = lr[2], A3 = lr[3];
  float k[16] = {A0.x,A0.y,A0.z,A0.w, A1.x,A1.y,A1.z,A1.w,
                 A2.x,A2.y,A2.z,A2.w, A3.x,A3.y,A3.z,A3.w};
  float s = 0.f;
  #pragma unroll
  for (int i = 0; i < 16; ++i) s += k[i] * cL[q * 16 + i];
  s += __shfl_xor(s, 1);
  s += __shfl_xor(s, 2);
  float u = 1.0f / s;
  float pc[16];
  #pragma unroll
  for (int i = 0; i < 16; ++i) pc[i] = k[i] * u;
  #pragma unroll
  for (int i = 0; i < 16; ++i) {
    pc[i] += __shfl_xor(pc[i], 4);
    pc[i] += __shfl_xor(pc[i], 8);
    pc[i] += __shfl_xor(pc[i], 16);
    pc[i] += __shfl_xor(pc[i], 32);
  }
  const int wv = t >> 6, l = t & 63;
  if (l < 4) {
    #pragma unroll
    for (int i = 0; i < 16; ++i) cps[wv][l * 16 + i] = pc[i];
  }
  __syncthreads();
  if (t < 64) {
    float tot = cps[0][t] + cps[1][t] + cps[2][t] + cps[3][t];
    atomicAdd(&colsums[IT * 64 + t], tot);
  }
}

// ---------------- K7: P = u5 * K * c5  (u5 = 1/(K c4)) ----------------
__global__ __launch_bounds__(256) void k7_final(const float* __restrict__ expK,
                                                const float* __restrict__ colsums,
                                                float* __restrict__ out) {
  __shared__ float c4L[64], c5L[64];
  const int t = threadIdx.x, b = blockIdx.x;
  if (t < 64) {
    c4L[t] = COLMASS / colsums[3 * 64 + t];
    c5L[t] = COLMASS / colsums[4 * 64 + t];
  }
  __syncthreads();
  const int q = t & 3;
  const int row = b * 64 + (t >> 2);
  const float4* lr = (const float4*)(expK + (size_t)row * 64 + q * 16);
  float4 A0 = lr[0], A1 = lr[1], A2 = lr[2], A3 = lr[3];
  float k[16] = {A0.x,A0.y,A0.z,A0.w, A1.x,A1.y,A1.z,A1.w,
                 A2.x,A2.y,A2.z,A2.w, A3.x,A3.y,A3.z,A3.w};
  float s = 0.f;
  #pragma unroll
  for (int i = 0; i < 16; ++i) s += k[i] * c4L[q * 16 + i];
  s += __shfl_xor(s, 1);
  s += __shfl_xor(s, 2);
  float u = 1.0f / s;
  float p[16];
  #pragma unroll
  for (int i = 0; i < 16; ++i) p[i] = u * k[i] * c5L[q * 16 + i];
  float4* op = (float4*)(out + (size_t)row * 64 + q * 16);
  op[0] = make_float4(p[0], p[1], p[2], p[3]);
  op[1] = make_float4(p[4], p[5], p[6], p[7]);
  op[2] = make_float4(p[8], p[9], p[10], p[11]);
  op[3] = make_float4(p[12], p[13], p[14], p[15]);
}

extern "C" void kernel_launch(void* const* d_in, const int* in_sizes, int n_in,
                              void* d_out, int out_size, void* d_ws, size_t ws_size,
                              hipStream_t stream) {
  const float* x  = (const float*)d_in[0];
  const float* ex = (const float*)d_in[1];
  float* out = (float*)d_out;
  float* ws  = (float*)d_ws;

  k1_norm_experts<<<64, 256, 0, stream>>>(ex, ws);
  k2_gram<<<64, 256, 0, stream>>>(ws, ws, out);
  k3_main<<<512, 256, 0, stream>>>(x, ws, ws, out);

  const float* expK = ws + OFF_EXPK;
  float* cols = ws + OFF_COLS;
  k4_iter<0><<<256, 256, 0, stream>>>(expK, cols);
  k4_iter<1><<<256, 256, 0, stream>>>(expK, cols);
  k4_iter<2><<<256, 256, 0, stream>>>(expK, cols);
  k4_iter<3><<<256, 256, 0, stream>>>(expK, cols);
  k4_iter<4><<<256, 256, 0, stream>>>(expK, cols);
  k7_final<<<256, 256, 0, stream>>>(expK, cols, out);
}

// Round 7
// 262.775 us; speedup vs baseline: 1.4200x; 1.0153x over previous
//
#include <hip/hip_runtime.h>
#include <math.h>

#define TOKENS 16384
#define EXPERTS 64
#define DIM 2048
#define BETA 0.5f
#define EPSILON 0.05f
#define EPSN 1e-12f
#define COLMASS 256.0f           // B/E = 16384/64

// ws layout (float offsets)
#define OFF_ENORM   0            // 64*2048 fp32 e_norm rows
#define OFF_BBF     131072       // 131072 ushorts: bf16 B in MFMA-fragment order
#define OFF_M       262144       // 64*64
#define OFF_EXPK    266240       // 16384*64  expK = exp(sim@M/eps)
#define OFF_COLS    1314816      // 5*64 column-sum accumulators

// out layout (float offsets): probs 0, sim 1048576, gram 2097152, gram_off 2101248

typedef __attribute__((ext_vector_type(8))) short short8v;   // 8 bf16 (4 VGPR)
typedef __attribute__((ext_vector_type(4))) float f32x4;

static __device__ __forceinline__ unsigned short f2bf(float f) {
  unsigned int u = __float_as_uint(f);
  u += 0x7FFFu + ((u >> 16) & 1u);   // round-to-nearest-even
  return (unsigned short)(u >> 16);
}

// ---------------- K1: normalize expert rows -> e_norm fp32 + bf16 B-fragment table ----------------
// Bbf layout: flat = (k>>5)*2048 + expert*32 + (k&31)
__global__ __launch_bounds__(256) void k1_norm_experts(const float* __restrict__ ex,
                                                       float* __restrict__ ws) {
  int j = blockIdx.x, t = threadIdx.x;
  // zero the Sinkhorn column-sum accumulators (ws is re-poisoned before every launch)
  if (j < 5 && t < 64) ws[OFF_COLS + j * 64 + t] = 0.0f;
  const float4* row4 = (const float4*)(ex + (size_t)j * DIM);
  float4 v0 = row4[t];
  float4 v1 = row4[t + 256];
  float ss = v0.x*v0.x + v0.y*v0.y + v0.z*v0.z + v0.w*v0.w
           + v1.x*v1.x + v1.y*v1.y + v1.z*v1.z + v1.w*v1.w;
  #pragma unroll
  for (int m = 1; m < 64; m <<= 1) ss += __shfl_xor(ss, m);
  __shared__ float red[4];
  int wv = t >> 6, ln = t & 63;
  if (ln == 0) red[wv] = ss;
  __syncthreads();
  float tot = red[0] + red[1] + red[2] + red[3];
  float sc = 1.0f / fmaxf(sqrtf(tot), EPSN);
  float4 w0 = make_float4(v0.x*sc, v0.y*sc, v0.z*sc, v0.w*sc);
  float4 w1 = make_float4(v1.x*sc, v1.y*sc, v1.z*sc, v1.w*sc);
  float4* en4 = (float4*)(ws + OFF_ENORM + (size_t)j * DIM);
  en4[t] = w0;
  en4[t + 256] = w1;
  unsigned short* Bb = (unsigned short*)(ws + OFF_BBF);
  int k0 = t * 4;
  int i0 = ((k0 >> 5) << 11) + (j << 5) + (k0 & 31);
  ushort4 u0; u0.x = f2bf(w0.x); u0.y = f2bf(w0.y); u0.z = f2bf(w0.z); u0.w = f2bf(w0.w);
  *(ushort4*)(Bb + i0) = u0;
  int k1v = (t + 256) * 4;
  int i1 = ((k1v >> 5) << 11) + (j << 5) + (k1v & 31);
  ushort4 u1; u1.x = f2bf(w1.x); u1.y = f2bf(w1.y); u1.z = f2bf(w1.z); u1.w = f2bf(w1.w);
  *(ushort4*)(Bb + i1) = u1;
}

// ---------------- K2: gram, gram_off, M = I - beta*gram_off ----------------
__global__ __launch_bounds__(256) void k2_gram(const float* __restrict__ wsr,
                                               float* __restrict__ ws,
                                               float* __restrict__ out) {
  __shared__ __align__(16) float ej[DIM];
  __shared__ float part[4][64];
  int j = blockIdx.x, t = threadIdx.x;
  const float4* en4 = (const float4*)(wsr + OFF_ENORM + (size_t)j * DIM);
  ((float4*)ej)[t] = en4[t];
  ((float4*)ej)[t + 256] = en4[t + 256];
  __syncthreads();
  int kk = t & 63, q = t >> 6;
  const float4* er = (const float4*)(wsr + OFF_ENORM + (size_t)kk * DIM) + q * 128;
  const float4* ejq = (const float4*)ej + q * 128;
  float p = 0.f;
  #pragma unroll 4
  for (int i = 0; i < 128; ++i) {
    float4 a = ejq[i], b = er[i];
    p += a.x*b.x + a.y*b.y + a.z*b.z + a.w*b.w;
  }
  part[q][kk] = p;
  __syncthreads();
  if (t < 64) {
    float g = part[0][t] + part[1][t] + part[2][t] + part[3][t];
    out[2097152 + j*64 + t] = g;
    float go = fmaxf(g - (t == j ? 1.0f : 0.0f), 0.0f);
    out[2101248 + j*64 + t] = go;
    ws[OFF_M + j*64 + t] = (t == j ? 1.0f : 0.0f) - BETA * go;
  }
}

// ---------------- K3: barrier-free direct-to-register MFMA GEMM ----------------
// grid 256 x 256 thr. Wave w owns rows blockIdx*64 + w*16 .. +15, all 64 cols.
// A loaded per-lane straight from x in MFMA fragment order (row l&15, k (l>>4)*8..+7).
// 4-buffer register pipeline, prefetch distance 3. No LDS / barriers in K-loop.
// Epilogue: row-norm scale, sim write, sim@M/eps, expK write, fused Sinkhorn iter 0.

#define LOADC(A0v, A1v, Bv0, Bv1, Bv2, Bv3, cc)                        \
  {                                                                    \
    const float* nx_ = xbase + (size_t)(cc) * 32;                      \
    A0v = *(const float4*)nx_;                                         \
    A1v = *(const float4*)(nx_ + 4);                                   \
    const unsigned short* bp_ = Bws + (size_t)(cc) * 2048 + bof;       \
    Bv0 = *(const short8v*)(bp_);                                      \
    Bv1 = *(const short8v*)(bp_ + 512);                                \
    Bv2 = *(const short8v*)(bp_ + 1024);                               \
    Bv3 = *(const short8v*)(bp_ + 1536);                               \
  }

#define COMPC(A0v, A1v, Bv0, Bv1, Bv2, Bv3)                                 \
  {                                                                         \
    nsq += A0v.x*A0v.x + A0v.y*A0v.y + A0v.z*A0v.z + A0v.w*A0v.w            \
         + A1v.x*A1v.x + A1v.y*A1v.y + A1v.z*A1v.z + A1v.w*A1v.w;           \
    short8v af_;                                                            \
    af_[0]=(short)f2bf(A0v.x); af_[1]=(short)f2bf(A0v.y);                   \
    af_[2]=(short)f2bf(A0v.z); af_[3]=(short)f2bf(A0v.w);                   \
    af_[4]=(short)f2bf(A1v.x); af_[5]=(short)f2bf(A1v.y);                   \
    af_[6]=(short)f2bf(A1v.z); af_[7]=(short)f2bf(A1v.w);                   \
    acc0 = __builtin_amdgcn_mfma_f32_16x16x32_bf16(af_, Bv0, acc0, 0, 0, 0);\
    acc1 = __builtin_amdgcn_mfma_f32_16x16x32_bf16(af_, Bv1, acc1, 0, 0, 0);\
    acc2 = __builtin_amdgcn_mfma_f32_16x16x32_bf16(af_, Bv2, acc2, 0, 0, 0);\
    acc3 = __builtin_amdgcn_mfma_f32_16x16x32_bf16(af_, Bv3, acc3, 0, 0, 0);\
  }

__global__ __launch_bounds__(256, 1) void k3_main(const float* __restrict__ x,
                                                  const float* __restrict__ wsr,
                                                  float* __restrict__ ws,
                                                  float* __restrict__ out,
                                                  float* __restrict__ colsums) {
  __shared__ __align__(16) float Ml[64 * 64];     // 16 KB
  __shared__ __align__(16) float simL[64 * 65];   // 16.6 KB, stride 65 (2-way max)
  __shared__ float cpsE[4][64];

  const int t = threadIdx.x;
  const int l = t & 63, w = t >> 6;
  const int r0 = blockIdx.x * 64;
  const int wr0 = r0 + w * 16;          // wave's global row base
  const int arow = l & 15;              // fragment row within wave tile
  const float* xbase = x + (size_t)(wr0 + arow) * DIM + ((l >> 4) << 3);
  const unsigned short* Bws = (const unsigned short*)(wsr + OFF_BBF);
  const int bof = ((l & 15) << 5) + ((l >> 4) << 3);

  f32x4 acc0 = {0.f,0.f,0.f,0.f}, acc1 = {0.f,0.f,0.f,0.f};
  f32x4 acc2 = {0.f,0.f,0.f,0.f}, acc3 = {0.f,0.f,0.f,0.f};
  float nsq = 0.f;

  float4 A00,A01,A10,A11,A20,A21,A30,A31;
  short8v B00,B01,B02,B03,B10,B11,B12,B13,B20,B21,B22,B23,B30,B31,B32,B33;
  LOADC(A00,A01,B00,B01,B02,B03, 0)
  LOADC(A10,A11,B10,B11,B12,B13, 1)
  LOADC(A20,A21,B20,B21,B22,B23, 2)
  for (int c = 0; c < 64; c += 4) {
    if (c + 3 < 64) LOADC(A30,A31,B30,B31,B32,B33, c+3)
    COMPC(A00,A01,B00,B01,B02,B03)
    if (c + 4 < 64) LOADC(A00,A01,B00,B01,B02,B03, c+4)
    COMPC(A10,A11,B10,B11,B12,B13)
    if (c + 5 < 64) LOADC(A10,A11,B10,B11,B12,B13, c+5)
    COMPC(A20,A21,B20,B21,B22,B23)
    if (c + 6 < 64) LOADC(A20,A21,B20,B21,B22,B23, c+6)
    COMPC(A30,A31,B30,B31,B32,B33)
  }

  // row-norm: lane partial covers row (l&15), k-slices (l>>4); reduce over lane^16, lane^32
  nsq += __shfl_xor(nsq, 16);
  nsq += __shfl_xor(nsq, 32);
  float scl = 1.0f / fmaxf(sqrtf(nsq), EPSN);   // valid for row l&15 (lanes 0..15 canonical)

  // sim = acc * scale -> simL + global
  float* simOut = out + 1048576;
  #pragma unroll
  for (int j = 0; j < 4; ++j) {
    int rr = ((l >> 4) << 2) + j;       // wave-local row
    float sc = __shfl(scl, rr);
    float4 sv = make_float4(acc0[j]*sc, acc1[j]*sc, acc2[j]*sc, acc3[j]*sc);
    int brow = w * 16 + rr;             // block-local row
    simL[brow * 65 + (l & 15)]      = sv.x;
    simL[brow * 65 + 16 + (l & 15)] = sv.y;
    simL[brow * 65 + 32 + (l & 15)] = sv.z;
    simL[brow * 65 + 48 + (l & 15)] = sv.w;
    size_t go = (size_t)(r0 + brow) * 64 + (l & 15);
    simOut[go]      = sv.x;
    simOut[go + 16] = sv.y;
    simOut[go + 32] = sv.z;
    simOut[go + 48] = sv.w;
  }
  // stage M
  {
    const float4* Mw = (const float4*)(wsr + OFF_M);
    float4* Ml4 = (float4*)Ml;
    #pragma unroll
    for (int s = 0; s < 4; ++s) Ml4[s * 256 + t] = Mw[s * 256 + t];
  }
  __syncthreads();

  // logK = sim @ M / eps ; expK = exp(logK); fused Sinkhorn iter 0
  const int tr = t >> 4, tc = t & 15;
  float lk[4][4] = {{0.f,0.f,0.f,0.f},{0.f,0.f,0.f,0.f},{0.f,0.f,0.f,0.f},{0.f,0.f,0.f,0.f}};
  #pragma unroll 8
  for (int j = 0; j < 64; ++j) {
    float4 mj = *(const float4*)&Ml[j * 64 + (tc << 2)];
    float s0 = simL[(4*tr + 0) * 65 + j];
    float s1 = simL[(4*tr + 1) * 65 + j];
    float s2 = simL[(4*tr + 2) * 65 + j];
    float s3 = simL[(4*tr + 3) * 65 + j];
    lk[0][0] += s0*mj.x; lk[0][1] += s0*mj.y; lk[0][2] += s0*mj.z; lk[0][3] += s0*mj.w;
    lk[1][0] += s1*mj.x; lk[1][1] += s1*mj.y; lk[1][2] += s1*mj.z; lk[1][3] += s1*mj.w;
    lk[2][0] += s2*mj.x; lk[2][1] += s2*mj.y; lk[2][2] += s2*mj.z; lk[2][3] += s2*mj.w;
    lk[3][0] += s3*mj.x; lk[3][1] += s3*mj.y; lk[3][2] += s3*mj.z; lk[3][3] += s3*mj.w;
  }
  float* expK = ws + OFF_EXPK;
  const float ie = 1.0f / EPSILON;
  float4 ek0 = make_float4(__expf(lk[0][0]*ie), __expf(lk[0][1]*ie), __expf(lk[0][2]*ie), __expf(lk[0][3]*ie));
  float4 ek1 = make_float4(__expf(lk[1][0]*ie), __expf(lk[1][1]*ie), __expf(lk[1][2]*ie), __expf(lk[1][3]*ie));
  float4 ek2 = make_float4(__expf(lk[2][0]*ie), __expf(lk[2][1]*ie), __expf(lk[2][2]*ie), __expf(lk[2][3]*ie));
  float4 ek3 = make_float4(__expf(lk[3][0]*ie), __expf(lk[3][1]*ie), __expf(lk[3][2]*ie), __expf(lk[3][3]*ie));
  *(float4*)(expK + (size_t)(r0 + 4*tr + 0) * 64 + (tc << 2)) = ek0;
  *(float4*)(expK + (size_t)(r0 + 4*tr + 1) * 64 + (tc << 2)) = ek1;
  *(float4*)(expK + (size_t)(r0 + 4*tr + 2) * 64 + (tc << 2)) = ek2;
  *(float4*)(expK + (size_t)(r0 + 4*tr + 3) * 64 + (tc << 2)) = ek3;
  // u = 1/rowsum (c0 = 1): reduce each row over the 16 tc lanes
  float u0 = ek0.x + ek0.y + ek0.z + ek0.w;
  float u1 = ek1.x + ek1.y + ek1.z + ek1.w;
  float u2 = ek2.x + ek2.y + ek2.z + ek2.w;
  float u3 = ek3.x + ek3.y + ek3.z + ek3.w;
  #pragma unroll
  for (int m = 1; m < 16; m <<= 1) {
    u0 += __shfl_xor(u0, m); u1 += __shfl_xor(u1, m);
    u2 += __shfl_xor(u2, m); u3 += __shfl_xor(u3, m);
  }
  u0 = 1.0f / u0; u1 = 1.0f / u1; u2 = 1.0f / u2; u3 = 1.0f / u3;
  // column partials for this lane's 4 cols, summed over the thread's 4 rows
  float4 pc = make_float4(u0*ek0.x + u1*ek1.x + u2*ek2.x + u3*ek3.x,
                          u0*ek0.y + u1*ek1.y + u2*ek2.y + u3*ek3.y,
                          u0*ek0.z + u1*ek1.z + u2*ek2.z + u3*ek3.z,
                          u0*ek0.w + u1*ek1.w + u2*ek2.w + u3*ek3.w);
  // reduce across the wave's 4 row-groups (lane^16, lane^32)
  pc.x += __shfl_xor(pc.x, 16); pc.y += __shfl_xor(pc.y, 16);
  pc.z += __shfl_xor(pc.z, 16); pc.w += __shfl_xor(pc.w, 16);
  pc.x += __shfl_xor(pc.x, 32); pc.y += __shfl_xor(pc.y, 32);
  pc.z += __shfl_xor(pc.z, 32); pc.w += __shfl_xor(pc.w, 32);
  if (l < 16) ((float4*)cpsE[w])[l] = pc;
  __syncthreads();
  if (t < 64) {
    float tot = cpsE[0][t] + cpsE[1][t] + cpsE[2][t] + cpsE[3][t];
    atomicAdd(&colsums[t], tot);       // colsums[0*64 + t]
  }
}

// ---------------- K4<IT>: one mult-Sinkhorn iteration (IT=1..4); launch boundary = barrier ----------------
template<int IT>
__global__ __launch_bounds__(256) void k4_iter(const float* __restrict__ expK,
                                               float* __restrict__ colsums) {
  __shared__ float cps[4][64];
  __shared__ float cL[64];
  const int t = threadIdx.x, b = blockIdx.x;
  if (t < 64) cL[t] = COLMASS / colsums[(IT - 1) * 64 + t];
  __syncthreads();
  const int q = t & 3;
  const int row = b * 64 + (t >> 2);
  const float4* lr = (const float4*)(expK + (size_t)row * 64 + q * 16);
  float4 A0 = lr[0], A1 = lr[1], A2 = lr[2], A3 = lr[3];
  float k[16] = {A0.x,A0.y,A0.z,A0.w, A1.x,A1.y,A1.z,A1.w,
                 A2.x,A2.y,A2.z,A2.w, A3.x,A3.y,A3.z,A3.w};
  float s = 0.f;
  #pragma unroll
  for (int i = 0; i < 16; ++i) s += k[i] * cL[q * 16 + i];
  s += __shfl_xor(s, 1);
  s += __shfl_xor(s, 2);
  float u = 1.0f / s;
  float pc[16];
  #pragma unroll
  for (int i = 0; i < 16; ++i) pc[i] = k[i] * u;
  #pragma unroll
  for (int i = 0; i < 16; ++i) {
    pc[i] += __shfl_xor(pc[i], 4);
    pc[i] += __shfl_xor(pc[i], 8);
    pc[i] += __shfl_xor(pc[i], 16);
    pc[i] += __shfl_xor(pc[i], 32);
  }
  const int wv = t >> 6, l = t & 63;
  if (l < 4) {
    #pragma unroll
    for (int i = 0; i < 16; ++i) cps[wv][l * 16 + i] = pc[i];
  }
  __syncthreads();
  if (t < 64) {
    float tot = cps[0][t] + cps[1][t] + cps[2][t] + cps[3][t];
    atomicAdd(&colsums[IT * 64 + t], tot);
  }
}

// ---------------- K7: P = u5 * K * c5  (u5 = 1/(K c4)) ----------------
__global__ __launch_bounds__(256) void k7_final(const float* __restrict__ expK,
                                                const float* __restrict__ colsums,
                                                float* __restrict__ out) {
  __shared__ float c4L[64], c5L[64];
  const int t = threadIdx.x, b = blockIdx.x;
  if (t < 64) {
    c4L[t] = COLMASS / colsums[3 * 64 + t];
    c5L[t] = COLMASS / colsums[4 * 64 + t];
  }
  __syncthreads();
  const int q = t & 3;
  const int row = b * 64 + (t >> 2);
  const float4* lr = (const float4*)(expK + (size_t)row * 64 + q * 16);
  float4 A0 = lr[0], A1 = lr[1], A2 = lr[2], A3 = lr[3];
  float k[16] = {A0.x,A0.y,A0.z,A0.w, A1.x,A1.y,A1.z,A1.w,
                 A2.x,A2.y,A2.z,A2.w, A3.x,A3.y,A3.z,A3.w};
  float s = 0.f;
  #pragma unroll
  for (int i = 0; i < 16; ++i) s += k[i] * c4L[q * 16 + i];
  s += __shfl_xor(s, 1);
  s += __shfl_xor(s, 2);
  float u = 1.0f / s;
  float p[16];
  #pragma unroll
  for (int i = 0; i < 16; ++i) p[i] = u * k[i] * c5L[q * 16 + i];
  float4* op = (float4*)(out + (size_t)row * 64 + q * 16);
  op[0] = make_float4(p[0], p[1], p[2], p[3]);
  op[1] = make_float4(p[4], p[5], p[6], p[7]);
  op[2] = make_float4(p[8], p[9], p[10], p[11]);
  op[3] = make_float4(p[12], p[13], p[14], p[15]);
}

extern "C" void kernel_launch(void* const* d_in, const int* in_sizes, int n_in,
                              void* d_out, int out_size, void* d_ws, size_t ws_size,
                              hipStream_t stream) {
  const float* x  = (const float*)d_in[0];
  const float* ex = (const float*)d_in[1];
  float* out = (float*)d_out;
  float* ws  = (float*)d_ws;

  float* cols = ws + OFF_COLS;
  const float* expK = ws + OFF_EXPK;

  k1_norm_experts<<<64, 256, 0, stream>>>(ex, ws);
  k2_gram<<<64, 256, 0, stream>>>(ws, ws, out);
  k3_main<<<256, 256, 0, stream>>>(x, ws, ws, out, cols);
  k4_iter<1><<<256, 256, 0, stream>>>(expK, cols);
  k4_iter<2><<<256, 256, 0, stream>>>(expK, cols);
  k4_iter<3><<<256, 256, 0, stream>>>(expK, cols);
  k4_iter<4><<<256, 256, 0, stream>>>(expK, cols);
  k7_final<<<256, 256, 0, stream>>>(expK, cols, out);
}